// Round 5
// baseline (89.702 us; speedup 1.0000x reference)
//
#include <hip/hip_runtime.h>
#include <hip/hip_cooperative_groups.h>

#define NDESC 384
#define NTYPES 4
#define BLOCK_ATOMS 256
#define NTHREADS 384

typedef unsigned int uint32;
typedef unsigned long long u64;

namespace cg = cooperative_groups;

// tanh(x) = 1 - 2/(1+e^{2x}); native v_exp_f32 + v_rcp_f32. Saturates to
// +/-1 for large |x|, no NaN for finite x. Abs err ~1e-6.
__device__ __forceinline__ float fast_tanh(float x) {
  float e = __builtin_amdgcn_exp2f(x * 2.8853900817779268f);   // e^{2x}
  return 1.0f - 2.0f * __builtin_amdgcn_rcpf(1.0f + e);
}

// One cooperative kernel:
//  A: per-block type ballots -> blockHist (types read ONCE, kept in regs)
//  grid.sync()
//  B: per-block scan of blockHist (L2-hot, wave-per-type) -> stable offsets
//  C: descriptor rows, 4 rows x 96 threads, float4 stores
__global__ __launch_bounds__(NTHREADS, 3) void fused_kernel(
    const float* __restrict__ coords, const int* __restrict__ types,
    const float* __restrict__ W, uint32* __restrict__ blockHist,
    float* __restrict__ descOut, float* __restrict__ confOut,
    float* __restrict__ countsOut, int n, int nb) {
  __shared__ float sW[3 * NDESC];
  __shared__ float sC[BLOCK_ATOMS][3];
  __shared__ uint32 sPos[BLOCK_ATOMS];
  __shared__ int sValid[BLOCK_ATOMS];
  __shared__ uint32 waveCnt[BLOCK_ATOMS / 64][NTYPES];
  __shared__ uint32 sTot[NTYPES];
  __shared__ uint32 sOff[NTYPES];

  int tid = threadIdx.x;
  int bid = blockIdx.x;
  int base = bid * BLOCK_ATOMS;

  // stage W (3x384) and this block's coords (256x3)
  for (int i = tid; i < 3 * NDESC; i += NTHREADS) sW[i] = W[i];
  for (int i = tid; i < BLOCK_ATOMS * 3; i += NTHREADS) {
    int g = base * 3 + i;
    sC[i / 3][i % 3] = (g < n * 3) ? coords[g] : 0.0f;
  }

  // ---- phase A: ballots = per-block histogram + within-block stable rank ----
  int idx = base + tid;
  int ty = -1;
  if (tid < BLOCK_ATOMS && idx < n) ty = types[idx];
  int wave = tid >> 6, lane = tid & 63;
  int myrank = 0;
  if (tid < BLOCK_ATOMS) {
    for (int t = 0; t < NTYPES; ++t) {
      u64 m = __ballot(ty == t);
      if (lane == 0) waveCnt[wave][t] = (uint32)__popcll(m);
      if (t == ty) myrank = (int)__popcll(m & ((1ull << lane) - 1ull));
    }
  }
  __syncthreads();
  if (tid < NTYPES) {
    uint32 s = 0;
    for (int w = 0; w < BLOCK_ATOMS / 64; ++w) s += waveCnt[w][tid];
    blockHist[bid * NTYPES + tid] = s;
  }
  if (tid < BLOCK_ATOMS && ty >= 0) {
    for (int w = 0; w < wave; ++w) myrank += (int)waveCnt[w][ty];
  }

  cg::this_grid().sync();

  // ---- phase B: per-block scan of blockHist; wave t handles type t ----
  if (wave < NTYPES) {
    int t = wave;
    uint32 tot = 0, pre = 0;
    for (int b = lane; b < nb; b += 64) {
      uint32 h = blockHist[b * NTYPES + t];
      tot += h;
      if (b < bid) pre += h;
    }
    for (int off = 32; off > 0; off >>= 1) {
      tot += __shfl_down(tot, off);
      pre += __shfl_down(pre, off);
    }
    if (lane == 0) { sTot[t] = tot; sOff[t] = pre; }
  }
  __syncthreads();
  if (tid < NTYPES) {
    uint32 b = 0;
    for (int t = 0; t < tid; ++t) b += sTot[t];
    sOff[tid] += b;                       // final base for this block, type tid
    if (bid == 0) countsOut[tid] = (float)sTot[tid];
  }
  __syncthreads();

  if (tid < BLOCK_ATOMS) {
    if (ty >= 0) {
      uint32 pos = sOff[ty] + (uint32)myrank;
      sPos[tid] = pos;
      sValid[tid] = 1;
      confOut[pos] = (float)(idx >> 6);   // idx / 64 atoms-per-conf
    } else {
      sPos[tid] = 0;
      sValid[tid] = 0;
    }
  }
  __syncthreads();

  // ---- phase C: 4 rows x 96 threads; thread handles cols [4c, 4c+4) ----
  int r = tid / 96;        // row slot 0..3
  int c = tid - r * 96;    // 0..95
  int d0 = 4 * c;
  float w00 = sW[d0], w01 = sW[d0 + 1], w02 = sW[d0 + 2], w03 = sW[d0 + 3];
  float w10 = sW[NDESC + d0], w11 = sW[NDESC + d0 + 1],
        w12 = sW[NDESC + d0 + 2], w13 = sW[NDESC + d0 + 3];
  float w20 = sW[2 * NDESC + d0], w21 = sW[2 * NDESC + d0 + 1],
        w22 = sW[2 * NDESC + d0 + 2], w23 = sW[2 * NDESC + d0 + 3];

  bool full = (base + BLOCK_ATOMS <= n);
  if (full) {
#pragma unroll 4
    for (int a0 = 0; a0 < BLOCK_ATOMS; a0 += 4) {
      int a = a0 + r;
      uint32 pos = sPos[a];
      float c0 = sC[a][0], c1 = sC[a][1], c2 = sC[a][2];
      float4 v;
      v.x = fast_tanh(c0 * w00 + c1 * w10 + c2 * w20);
      v.y = fast_tanh(c0 * w01 + c1 * w11 + c2 * w21);
      v.z = fast_tanh(c0 * w02 + c1 * w12 + c2 * w22);
      v.w = fast_tanh(c0 * w03 + c1 * w13 + c2 * w23);
      *reinterpret_cast<float4*>(descOut + (size_t)pos * NDESC + d0) = v;
    }
  } else {
    for (int a0 = 0; a0 < BLOCK_ATOMS; a0 += 4) {
      int a = a0 + r;
      uint32 pos = sPos[a];
      float c0 = sC[a][0], c1 = sC[a][1], c2 = sC[a][2];
      float4 v;
      v.x = fast_tanh(c0 * w00 + c1 * w10 + c2 * w20);
      v.y = fast_tanh(c0 * w01 + c1 * w11 + c2 * w21);
      v.z = fast_tanh(c0 * w02 + c1 * w12 + c2 * w22);
      v.w = fast_tanh(c0 * w03 + c1 * w13 + c2 * w23);
      if (sValid[a]) {
        *reinterpret_cast<float4*>(descOut + (size_t)pos * NDESC + d0) = v;
      }
    }
  }
}

extern "C" void kernel_launch(void* const* d_in, const int* in_sizes, int n_in,
                              void* d_out, int out_size, void* d_ws, size_t ws_size,
                              hipStream_t stream) {
  const float* coords = (const float*)d_in[0];
  const int* types = (const int*)d_in[1];
  const float* W = (const float*)d_in[2];

  int n = in_sizes[1];                      // total atoms (= n_confs * 64)
  int nb = (n + BLOCK_ATOMS - 1) / BLOCK_ATOMS;

  uint32* blockHist = (uint32*)d_ws;        // nb * 4 uints

  float* descOut = (float*)d_out;
  float* confOut = descOut + (size_t)n * NDESC;
  float* countsOut = confOut + n;

  void* args[] = {(void*)&coords, (void*)&types, (void*)&W, (void*)&blockHist,
                  (void*)&descOut, (void*)&confOut, (void*)&countsOut,
                  (void*)&n, (void*)&nb};
  hipLaunchCooperativeKernel((const void*)fused_kernel, dim3(nb), dim3(NTHREADS),
                             args, 0, stream);
}

// Round 6
// 47.213 us; speedup vs baseline: 1.8999x; 1.8999x over previous
//
#include <hip/hip_runtime.h>

#define NDESC 384
#define NTYPES 4
#define BLOCK_ATOMS 256
#define NTHREADS 384

typedef unsigned int uint32;
typedef unsigned long long u64;

// tanh(x) = 1 - 2/(1+e^{2x}); native v_exp_f32 + v_rcp_f32. Abs err ~1e-6.
__device__ __forceinline__ float fast_tanh(float x) {
  float e = __builtin_amdgcn_exp2f(x * 2.8853900817779268f);   // e^{2x}
  return 1.0f - 2.0f * __builtin_amdgcn_rcpf(1.0f + e);
}

// ---------------- Kernel 1: per-block type histogram (ballot-based) --------
__global__ __launch_bounds__(BLOCK_ATOMS) void hist_kernel(
    const int* __restrict__ types, uint32* __restrict__ blockHist, int n) {
  __shared__ uint32 waveCnt[BLOCK_ATOMS / 64][NTYPES];
  int tid = threadIdx.x;
  int idx = blockIdx.x * BLOCK_ATOMS + tid;
  int ty = (idx < n) ? types[idx] : -1;
  int wave = tid >> 6, lane = tid & 63;
  for (int t = 0; t < NTYPES; ++t) {
    u64 m = __ballot(ty == t);
    if (lane == 0) waveCnt[wave][t] = (uint32)__popcll(m);
  }
  __syncthreads();
  if (tid < NTYPES) {
    uint32 s = 0;
    for (int w = 0; w < BLOCK_ATOMS / 64; ++w) s += waveCnt[w][tid];
    blockHist[blockIdx.x * NTYPES + tid] = s;
  }
}

// ---------------- Kernel 2: fused scan + rank + descriptor + scatter -------
// Each block scans blockHist itself (8 KB, L2-hot) -> no separate scan kernel,
// no grid sync. Phase C iterates in RANK order so stores stream contiguously
// within each type partition (4 monotone streams per block).
__global__ __launch_bounds__(NTHREADS) void main_kernel(
    const float* __restrict__ coords, const int* __restrict__ types,
    const float* __restrict__ W, const uint32* __restrict__ blockHist,
    float* __restrict__ descOut, float* __restrict__ confOut,
    float* __restrict__ countsOut, int n, int nb) {
  __shared__ float sW[3 * NDESC];
  __shared__ float sC[BLOCK_ATOMS][3];
  __shared__ uint32 sRankPos[BLOCK_ATOMS];   // block-rank -> global position
  __shared__ uint32 sRankAtom[BLOCK_ATOMS];  // block-rank -> atom tid
  __shared__ uint32 waveCnt[BLOCK_ATOMS / 64][NTYPES];
  __shared__ uint32 sTot[NTYPES];   // global per-type totals
  __shared__ uint32 sOff[NTYPES];   // this block's global base per type
  __shared__ uint32 sCum[NTYPES];   // within-block exclusive type prefix

  int tid = threadIdx.x;
  int bid = blockIdx.x;
  int base = bid * BLOCK_ATOMS;

  // stage W (3x384) and this block's coords (256x3)
  for (int i = tid; i < 3 * NDESC; i += NTHREADS) sW[i] = W[i];
  for (int i = tid; i < BLOCK_ATOMS * 3; i += NTHREADS) {
    int g = base * 3 + i;
    sC[i / 3][i % 3] = (g < n * 3) ? coords[g] : 0.0f;
  }

  // ---- ballots: within-block per-wave counts + per-lane stable rank ----
  int idx = base + tid;
  int ty = -1;
  if (tid < BLOCK_ATOMS && idx < n) ty = types[idx];
  int wave = tid >> 6, lane = tid & 63;
  int myrank = 0;
  if (tid < BLOCK_ATOMS) {
    for (int t = 0; t < NTYPES; ++t) {
      u64 m = __ballot(ty == t);
      if (lane == 0) waveCnt[wave][t] = (uint32)__popcll(m);
      if (t == ty) myrank = (int)__popcll(m & ((1ull << lane) - 1ull));
    }
  }

  // ---- per-block scan of blockHist: wave t handles type t ----
  if (wave < NTYPES) {
    int t = wave;
    uint32 tot = 0, pre = 0;
    for (int b = lane; b < nb; b += 64) {
      uint32 h = blockHist[b * NTYPES + t];
      tot += h;
      if (b < bid) pre += h;
    }
    for (int off = 32; off > 0; off >>= 1) {
      tot += __shfl_down(tot, off);
      pre += __shfl_down(pre, off);
    }
    if (lane == 0) { sTot[t] = tot; sOff[t] = pre; }
  }
  __syncthreads();
  if (tid == 0) {
    uint32 b = 0, c = 0;
    for (int t = 0; t < NTYPES; ++t) {
      sOff[t] += b;
      b += sTot[t];
      uint32 cnt = 0;
      for (int w = 0; w < BLOCK_ATOMS / 64; ++w) cnt += waveCnt[w][t];
      sCum[t] = c;
      c += cnt;
    }
  }
  if (bid == 0 && tid < NTYPES) countsOut[tid] = (float)sTot[tid];
  __syncthreads();

  // ---- scatter rank tables + conf ids ----
  if (tid < BLOCK_ATOMS && ty >= 0) {
    uint32 fullrank = (uint32)myrank;
    for (int w = 0; w < wave; ++w) fullrank += waveCnt[w][ty];
    uint32 pos = sOff[ty] + fullrank;
    uint32 brk = sCum[ty] + fullrank;   // rank within block, 0..valid-1
    sRankPos[brk] = pos;
    sRankAtom[brk] = (uint32)tid;
    confOut[pos] = (float)(idx >> 6);   // idx / 64 atoms-per-conf
  }
  __syncthreads();

  // ---- phase C: rank order, 4 ranks x 96 threads, float4 stores ----
  int r = tid / 96;        // rank slot 0..3
  int c = tid - r * 96;    // 0..95
  int d0 = 4 * c;
  float w00 = sW[d0], w01 = sW[d0 + 1], w02 = sW[d0 + 2], w03 = sW[d0 + 3];
  float w10 = sW[NDESC + d0], w11 = sW[NDESC + d0 + 1],
        w12 = sW[NDESC + d0 + 2], w13 = sW[NDESC + d0 + 3];
  float w20 = sW[2 * NDESC + d0], w21 = sW[2 * NDESC + d0 + 1],
        w22 = sW[2 * NDESC + d0 + 2], w23 = sW[2 * NDESC + d0 + 3];

  int valid = n - base;
  if (valid > BLOCK_ATOMS) valid = BLOCK_ATOMS;

  if (valid == BLOCK_ATOMS) {
#pragma unroll 4
    for (int k0 = 0; k0 < BLOCK_ATOMS; k0 += 4) {
      int k = k0 + r;
      uint32 a = sRankAtom[k];
      uint32 pos = sRankPos[k];
      float c0 = sC[a][0], c1 = sC[a][1], c2 = sC[a][2];
      float4 v;
      v.x = fast_tanh(c0 * w00 + c1 * w10 + c2 * w20);
      v.y = fast_tanh(c0 * w01 + c1 * w11 + c2 * w21);
      v.z = fast_tanh(c0 * w02 + c1 * w12 + c2 * w22);
      v.w = fast_tanh(c0 * w03 + c1 * w13 + c2 * w23);
      *reinterpret_cast<float4*>(descOut + (size_t)pos * NDESC + d0) = v;
    }
  } else {
    for (int k0 = 0; k0 < BLOCK_ATOMS; k0 += 4) {
      int k = k0 + r;
      if (k < valid) {
        uint32 a = sRankAtom[k];
        uint32 pos = sRankPos[k];
        float c0 = sC[a][0], c1 = sC[a][1], c2 = sC[a][2];
        float4 v;
        v.x = fast_tanh(c0 * w00 + c1 * w10 + c2 * w20);
        v.y = fast_tanh(c0 * w01 + c1 * w11 + c2 * w21);
        v.z = fast_tanh(c0 * w02 + c1 * w12 + c2 * w22);
        v.w = fast_tanh(c0 * w03 + c1 * w13 + c2 * w23);
        *reinterpret_cast<float4*>(descOut + (size_t)pos * NDESC + d0) = v;
      }
    }
  }
}

extern "C" void kernel_launch(void* const* d_in, const int* in_sizes, int n_in,
                              void* d_out, int out_size, void* d_ws, size_t ws_size,
                              hipStream_t stream) {
  const float* coords = (const float*)d_in[0];
  const int* types = (const int*)d_in[1];
  const float* W = (const float*)d_in[2];

  int n = in_sizes[1];                      // total atoms (= n_confs * 64)
  int nb = (n + BLOCK_ATOMS - 1) / BLOCK_ATOMS;

  uint32* blockHist = (uint32*)d_ws;        // nb * 4 uints

  float* descOut = (float*)d_out;
  float* confOut = descOut + (size_t)n * NDESC;
  float* countsOut = confOut + n;

  hipLaunchKernelGGL(hist_kernel, dim3(nb), dim3(BLOCK_ATOMS), 0, stream,
                     types, blockHist, n);
  hipLaunchKernelGGL(main_kernel, dim3(nb), dim3(NTHREADS), 0, stream,
                     coords, types, W, blockHist, descOut, confOut, countsOut,
                     n, nb);
}